// Round 18
// baseline (466.237 us; speedup 1.0000x reference)
//
#include <hip/hip_runtime.h>

#define B_  8
#define T_  1024
#define D_  1024
#define H_  16
#define DK_ 64
#define C_  8
#define N_  (B_*T_)   // 8192 rows

typedef __attribute__((ext_vector_type(8))) short bf16x8;
typedef __attribute__((ext_vector_type(4))) float f32x4;
typedef __attribute__((ext_vector_type(8))) unsigned short u16x8;
typedef __attribute__((ext_vector_type(4))) unsigned short u16x4;

__device__ __forceinline__ float bf2f(unsigned short u) {
  union { unsigned int i; float f; } x; x.i = ((unsigned int)u) << 16; return x.f;
}
__device__ __forceinline__ unsigned short f2bf(float f) {
  union { float f; unsigned int i; } x; x.f = f;
  unsigned int r = (x.i + 0x7fffu + ((x.i >> 16) & 1u)) >> 16;
  return (unsigned short)r;
}
__device__ __forceinline__ unsigned short f2h(float f) {
  union { _Float16 h; unsigned short u; } x; x.h = (_Float16)f; return x.u;
}
__device__ __forceinline__ float h2f(unsigned short u) {
  union { _Float16 h; unsigned short u; } x; x.u = u; return (float)x.h;
}

// async global->LDS, 16B per lane. LDS dest is wave-uniform base + lane*16.
__device__ __forceinline__ void gl_lds16(const unsigned short* g, unsigned short* l) {
  __builtin_amdgcn_global_load_lds(
      (const __attribute__((address_space(1))) unsigned int*)g,
      (__attribute__((address_space(3))) unsigned int*)l,
      16, 0, 0);
}

// ---- fused fp32->bf16 for query/key/value (3 segments, 1 launch) ----------
__global__ __launch_bounds__(256) void cvt_qkv(
    const float* __restrict__ q, const float* __restrict__ k,
    const float* __restrict__ v, unsigned short* __restrict__ qo,
    unsigned short* __restrict__ ko, unsigned short* __restrict__ vo, int n4) {
  int seg = blockIdx.x >> 10;              // 1024 blocks per segment
  int bid = blockIdx.x & 1023;
  const float* in = (seg == 0) ? q : (seg == 1) ? k : v;
  unsigned short* out = (seg == 0) ? qo : (seg == 1) ? ko : vo;
  int tid = bid * blockDim.x + threadIdx.x;
  int stride = 1024 * 256;
  const float4* in4 = (const float4*)in;
  u16x4* out4 = (u16x4*)out;
  for (int i = tid; i < n4; i += stride) {
    float4 vv = in4[i];
    u16x4 o = { f2bf(vv.x), f2bf(vv.y), f2bf(vv.z), f2bf(vv.w) };
    out4[i] = o;
  }
}

// ---- fused fp32->bf16 for the 4 weight matrices (1 launch) ----------------
__global__ __launch_bounds__(256) void cvt_w(
    const float* __restrict__ w0, const float* __restrict__ w1,
    const float* __restrict__ w2, const float* __restrict__ w3,
    unsigned short* __restrict__ o0, unsigned short* __restrict__ o1,
    unsigned short* __restrict__ o2, unsigned short* __restrict__ o3, int n4) {
  int seg = blockIdx.x >> 8;               // 256 blocks per segment
  int bid = blockIdx.x & 255;
  const float* in = (seg == 0) ? w0 : (seg == 1) ? w1 : (seg == 2) ? w2 : w3;
  unsigned short* out = (seg == 0) ? o0 : (seg == 1) ? o1 : (seg == 2) ? o2 : o3;
  int tid = bid * blockDim.x + threadIdx.x;
  int stride = 256 * 256;
  const float4* in4 = (const float4*)in;
  u16x4* out4 = (u16x4*)out;
  for (int i = tid; i < n4; i += stride) {
    float4 vv = in4[i];
    u16x4 o = { f2bf(vv.x), f2bf(vv.y), f2bf(vv.z), f2bf(vv.w) };
    out4[i] = o;
  }
}

// ---- transposeQa body: qa [B][T][T][C] fp32 -> qat [B][C][T][T] fp16 ------
__device__ __forceinline__ void tqa_body(
    int bid, const float* __restrict__ qa, unsigned short* __restrict__ qat,
    float (*L)[132]) {
  int b = bid >> 10, q = bid & 1023;
  int t = threadIdx.x;
  const float* src = qa + ((size_t)(b*T_ + q))*T_*C_;
  for (int ch = 0; ch < 8; ++ch) {
    int k0 = ch*128;
    float4 v = *(const float4*)(src + (size_t)(k0 + (t>>1))*C_ + (t&1)*4);
    int c4 = (t&1)*4, kk = t>>1;
    L[c4+0][kk] = v.x; L[c4+1][kk] = v.y; L[c4+2][kk] = v.z; L[c4+3][kk] = v.w;
    __syncthreads();
    int c = t >> 5, kk2 = (t&31)*4;
    float4 p = *(const float4*)&L[c][kk2];
    u16x4 o = { f2h(p.x), f2h(p.y), f2h(p.z), f2h(p.w) };
    *(u16x4*)(qat + ((size_t)(b*C_ + c)*T_ + q)*T_ + k0 + kk2) = o;
    __syncthreads();
  }
}

// ---- transposeV body: V [b*T+t][h*64+d] -> Vt [(b*H+h)*64+d][T] -----------
__device__ __forceinline__ void tv_body(
    int bid, const unsigned short* __restrict__ V, unsigned short* __restrict__ Vt,
    unsigned short (*L)[72]) {
  int tt = bid & 15;
  int bh = bid >> 4;               // 0..127
  int b = bh >> 4, h = bh & 15;
  int r  = threadIdx.x >> 3;       // 0..31
  int c8 = (threadIdx.x & 7) * 8;
  const unsigned short* src = V + ((size_t)(b*T_ + tt*64))*D_ + h*64;
#pragma unroll
  for (int p = 0; p < 2; ++p) {
    int rr = r + p*32;
    u16x8 v = *(const u16x8*)(src + (size_t)rr*D_ + c8);
    *(u16x8*)&L[rr][c8] = v;
  }
  __syncthreads();
  unsigned short* dst = Vt + ((size_t)bh*64)*T_ + tt*64;
#pragma unroll
  for (int p = 0; p < 2; ++p) {
    int d = r + p*32;
    u16x8 o;
#pragma unroll
    for (int i = 0; i < 8; ++i) o[i] = L[c8 + i][d];
    *(u16x8*)(dst + (size_t)d*T_ + c8) = o;
  }
}

// ---- fused transposeV + transposeQa (both pure-BW streamers, same regime) -
__global__ __launch_bounds__(256) void tv_tqa(
    const unsigned short* __restrict__ V, unsigned short* __restrict__ Vt,
    const float* __restrict__ qa, unsigned short* __restrict__ qat) {
  __shared__ __align__(16) unsigned char smem[9216];  // union of both bodies
  if (blockIdx.x < 2048) {
    tv_body(blockIdx.x, V, Vt, (unsigned short(*)[72])smem);
  } else {
    tqa_body(blockIdx.x - 2048, qa, qat, (float(*)[132])smem);
  }
}

// standalone versions (fallback path)
__global__ __launch_bounds__(256) void transposeQa(
    const float* __restrict__ qa, unsigned short* __restrict__ qat) {
  __shared__ float L[8][132];
  tqa_body(blockIdx.x, qa, qat, L);
}
__global__ __launch_bounds__(256) void transposeV(
    const unsigned short* __restrict__ V, unsigned short* __restrict__ Vt) {
  __shared__ unsigned short L[64][72];
  tv_body(blockIdx.x, V, Vt, L);
}

// ---------------- m97-structure GEMM body: 128x128 tile, BK=32, 4 waves ----
template <bool OUT_F32>
__device__ __forceinline__ void gemm_body(
    int blockid, const unsigned short* __restrict__ X,
    const unsigned short* __restrict__ W, const float* __restrict__ bias,
    void* __restrict__ Yv, unsigned short* As, unsigned short* Bs) {
  int orig = (blockid & 7) * 64 + (blockid >> 3);   // bijective (512%8==0)
  int bm = orig >> 3, bn = orig & 7;
  int t = threadIdx.x, lane = t & 63, w = t >> 6;
  int wr = w >> 1, wc = w & 1;
  int r16 = lane & 15, kg = lane >> 4;

  int srow0 = lane >> 2;
  int scol  = (lane & 3) * 8;
  const unsigned short* Ab = X + (size_t)(bm*128)*D_ + scol;
  const unsigned short* Bb = W + (size_t)(bn*128)*D_ + scol;

  f32x4 acc[4][4];
#pragma unroll
  for (int m = 0; m < 4; ++m)
#pragma unroll
    for (int n = 0; n < 4; ++n) acc[m][n] = (f32x4){0.f,0.f,0.f,0.f};

  for (int k0 = 0; k0 < D_; k0 += 32) {
    __syncthreads();
#pragma unroll
    for (int c = 0; c < 2; ++c) {
      int cidx = w*2 + c;
      int row = cidx*16 + srow0;
      gl_lds16(Ab + (size_t)row*D_ + k0, As + cidx*512);
      gl_lds16(Bb + (size_t)row*D_ + k0, Bs + cidx*512);
    }
    __syncthreads();

    bf16x8 a[4], bb[4];
#pragma unroll
    for (int m = 0; m < 4; ++m)
      a[m] = *(const bf16x8*)(As + (wr*64 + m*16 + r16)*32 + kg*8);
#pragma unroll
    for (int n = 0; n < 4; ++n)
      bb[n] = *(const bf16x8*)(Bs + (wc*64 + n*16 + r16)*32 + kg*8);
#pragma unroll
    for (int m = 0; m < 4; ++m)
#pragma unroll
      for (int n = 0; n < 4; ++n)
        acc[m][n] = __builtin_amdgcn_mfma_f32_16x16x32_bf16(a[m], bb[n], acc[m][n], 0, 0, 0);
  }

#pragma unroll
  for (int n = 0; n < 4; ++n) {
    int col = bn*128 + wc*64 + n*16 + r16;
    float bv = bias[col];
#pragma unroll
    for (int m = 0; m < 4; ++m) {
      int row0 = bm*128 + wr*64 + m*16 + kg*4;
#pragma unroll
      for (int jj = 0; jj < 4; ++jj) {
        float rv = acc[m][n][jj] + bv;
        if constexpr (OUT_F32)
          ((float*)Yv)[(size_t)(row0 + jj)*D_ + col] = rv;
        else
          ((unsigned short*)Yv)[(size_t)(row0 + jj)*D_ + col] = f2bf(rv);
      }
    }
  }
}

// single GEMM (used for the output projection)
template <bool OUT_F32>
__global__ __launch_bounds__(256) void gemm_lds(
    const unsigned short* __restrict__ X, const unsigned short* __restrict__ W,
    const float* __restrict__ bias, void* __restrict__ Yv) {
  __shared__ __align__(16) unsigned short As[128*32];
  __shared__ __align__(16) unsigned short Bs[128*32];
  gemm_body<OUT_F32>(blockIdx.x, X, W, bias, Yv, As, Bs);
}

// fused Q/K/V projections: grid = 3*512, segment-decoded
__global__ __launch_bounds__(256) void gemm_qkv(
    const unsigned short* __restrict__ Xq, const unsigned short* __restrict__ Xk,
    const unsigned short* __restrict__ Xv,
    const unsigned short* __restrict__ Wq2, const unsigned short* __restrict__ Wk2,
    const unsigned short* __restrict__ Wv2,
    const float* __restrict__ bq2, const float* __restrict__ bk2,
    const float* __restrict__ bv2,
    unsigned short* __restrict__ Yq, unsigned short* __restrict__ Yk,
    unsigned short* __restrict__ Yv2) {
  __shared__ __align__(16) unsigned short As[128*32];
  __shared__ __align__(16) unsigned short Bs[128*32];
  int seg = blockIdx.x >> 9, inner = blockIdx.x & 511;
  const unsigned short* X = (seg == 0) ? Xq : (seg == 1) ? Xk : Xv;
  const unsigned short* W = (seg == 0) ? Wq2 : (seg == 1) ? Wk2 : Wv2;
  const float* bias = (seg == 0) ? bq2 : (seg == 1) ? bk2 : bv2;
  unsigned short* Y = (seg == 0) ? Yq : (seg == 1) ? Yk : Yv2;
  gemm_body<false>(inner, X, W, bias, Y, As, Bs);
}

// ---------------- attn5s: P redistribution via shuffles (no P LDS) ---------
// block = (b,h,128 q-rows); wave w owns q = q0w..q0w+31 (2 q-frags of 16).
// K/V double-buffered LDS (32 KB total -> up to 5 blocks/CU); swapped QK^T;
// P pairs pk[j] (global k-pair kt*8+kg*2+c at j=2kt+c, row q=r16) are
// redistributed to PV A-fragments IN REGISTERS:
//   pa0 pair g=kg*4+i, pa1 pair 16+kg*4+i; source lane = r16+16*kg_src with
//   kg_src = 2*(kg&1) (+1 for the hi half); register select by kg>>1.
// All shfl register indices compile-time (rule #20); values consumed
// immediately (short live ranges - avoids the R10/R12/R16 spill mode).
// launch_bounds stays (256,3): VGPR budget untouched; HW takes extra blocks.
__global__ __launch_bounds__(256, 3) void attn5s(
    const unsigned short* __restrict__ Q, const unsigned short* __restrict__ K,
    const unsigned short* __restrict__ Vt, const unsigned short* __restrict__ qat,
    const int* __restrict__ mask, unsigned short* __restrict__ X) {
  int swzid = ((blockIdx.x & 7) << 7) | (blockIdx.x >> 3);  // XCD-chunked, 1024
  int qt = swzid & 7, h = (swzid >> 3) & 15, b = swzid >> 7;
  int w = threadIdx.x >> 6, lane = threadIdx.x & 63;
  int r16 = lane & 15, kg = lane >> 4;
  int q0w = qt*128 + w*32;
  int bh = b*H_ + h;

  __shared__ unsigned short Ks[2][64][64];    // 16 KB
  __shared__ unsigned short Vs[2][64][64];    // 16 KB   (total 32 KB)

  int rl = lane >> 3;
  int eo = ((lane & 7) * 8) ^ (rl << 3);     // swizzled elem offset in row
  const unsigned short* Kb = K + ((size_t)b*T_)*D_ + h*DK_;
  const unsigned short* Vb = Vt + ((size_t)bh*DK_)*T_;

  int sw16 = (r16 & 7) << 4;
  int ko0 = ((kg*16 +  0) ^ sw16) >> 1;      // elem offset, half 0
  int ko1 = ((kg*16 + 64) ^ sw16) >> 1;      // elem offset, half 1

  // shuffle geometry for P redistribution
  int srcA = r16 + ((kg & 1) << 5);          // lane holding kg_src = 2*(kg&1)
  int srcB = srcA + 16;                      // kg_src = 2*(kg&1)+1
  bool sello = (kg < 2);

  bf16x8 qfr[2][2];
#pragma unroll
  for (int qf = 0; qf < 2; ++qf) {
    const unsigned short* qrow = Q + ((size_t)b*T_ + q0w + qf*16 + r16)*D_ + h*DK_ + kg*8;
    qfr[qf][0] = *(const bf16x8*)qrow;
    qfr[qf][1] = *(const bf16x8*)(qrow + 32);
  }

  f32x4 acc[2][4];
#pragma unroll
  for (int qf = 0; qf < 2; ++qf)
#pragma unroll
    for (int db = 0; db < 4; ++db) acc[qf][db] = (f32x4){0.f,0.f,0.f,0.f};
  float mold[2] = {-3e38f, -3e38f};
  float lpart[2] = {0.f, 0.f};    // per-lane partial denominator (16 k each)

  const int* mrow = mask + b*T_;
  const unsigned short* qab0 = qat + ((size_t)((b*C_ + h)*T_) + q0w + r16)*T_;

  // prologue: stage tile 0 into buffer 0
#pragma unroll
  for (int c = 0; c < 2; ++c) {
    int cc = w*2 + c;
    gl_lds16(Kb + (size_t)(cc*8 + rl)*D_ + eo, &Ks[0][cc*8][0]);
    gl_lds16(Vb + (size_t)(cc*8 + rl)*T_ + eo, &Vs[0][cc*8][0]);
  }
  __syncthreads();

  for (int t = 0; t < 16; ++t) {
    int k0 = t*64, bb = t & 1;
    // ---- stage next tile into other buffer ----
    if (t < 15) {
      int kn = k0 + 64, nb = bb ^ 1;
#pragma unroll
      for (int c = 0; c < 2; ++c) {
        int cc = w*2 + c;
        gl_lds16(Kb + (size_t)(kn + cc*8 + rl)*D_ + eo, &Ks[nb][cc*8][0]);
        gl_lds16(Vb + (size_t)(cc*8 + rl)*T_ + kn + eo, &Vs[nb][cc*8][0]);
      }
    }
    // ---- qa + mask loads ----
    u16x4 qv[2][4];
    if (h < C_) {
#pragma unroll
      for (int qf = 0; qf < 2; ++qf)
#pragma unroll
        for (int kt = 0; kt < 4; ++kt)
          qv[qf][kt] = *(const u16x4*)(qab0 + (size_t)qf*16*T_ + k0 + kt*16 + kg*4);
    }
    int mk = mrow[k0 + lane];
    unsigned long long bits = __ballot(mk != 0);

    // ---- QK^T from LDS: s[qf][kt], rows=k cols=q ----
    f32x4 s[2][4];
#pragma unroll
    for (int kt = 0; kt < 4; ++kt) {
      bf16x8 kf0 = *(const bf16x8*)&Ks[bb][kt*16 + r16][ko0];
      bf16x8 kf1 = *(const bf16x8*)&Ks[bb][kt*16 + r16][ko1];
#pragma unroll
      for (int qf = 0; qf < 2; ++qf) {
        f32x4 z = (f32x4){0.f,0.f,0.f,0.f};
        z = __builtin_amdgcn_mfma_f32_16x16x32_bf16(kf0, qfr[qf][0], z, 0, 0, 0);
        z = __builtin_amdgcn_mfma_f32_16x16x32_bf16(kf1, qfr[qf][1], z, 0, 0, 0);
        s[qf][kt] = z;
      }
    }

    // ---- scale + bias + mask; row-max per q-frag (2 shfl each) ----
    float pmaxq[2];
#pragma unroll
    for (int qf = 0; qf < 2; ++qf) {
      float pmax = -3e38f;
#pragma unroll
      for (int kt = 0; kt < 4; ++kt)
#pragma unroll
        for (int jj = 0; jj < 4; ++jj) {
          float v = s[qf][kt][jj] * 0.125f;
          if (h < C_) v += 5.0f * h2f(qv[qf][kt][jj]);
          int idx = kt*16 + kg*4 + jj;
          v = ((bits >> idx) & 1ULL) ? v : -1e9f;
          s[qf][kt][jj] = v;
          pmax = fmaxf(pmax, v);
        }
      pmax = fmaxf(pmax, __shfl_xor(pmax, 16, 64));
      pmax = fmaxf(pmax, __shfl_xor(pmax, 32, 64));
      pmaxq[qf] = pmax;
    }
    // ---- defer-max: rescale only when a row's max grew by > 8 ----
    if (!__all(pmaxq[0] - mold[0] <= 8.0f && pmaxq[1] - mold[1] <= 8.0f)) {
#pragma unroll
      for (int qf = 0; qf < 2; ++qf) {
        float mnew = fmaxf(mold[qf], pmaxq[qf]);
        float sc = __expf(mold[qf] - mnew);
        mold[qf] = mnew;
        lpart[qf] *= sc;
        float scq[4];
#pragma unroll
        for (int jj = 0; jj < 4; ++jj) scq[jj] = __shfl(sc, kg*4 + jj, 64);
#pragma unroll
        for (int db = 0; db < 4; ++db)
#pragma unroll
          for (int jj = 0; jj < 4; ++jj) acc[qf][db][jj] *= scq[jj];
      }
    }
    // ---- per qf: exp + pack, shuffle-redistribute, PV (no LDS, no fence) --
#pragma unroll
    for (int qf = 0; qf < 2; ++qf) {
      unsigned int pk[8];
#pragma unroll
      for (int kt = 0; kt < 4; ++kt) {
        float p0 = __expf(s[qf][kt][0] - mold[qf]), p1 = __expf(s[qf][kt][1] - mold[qf]);
        float p2 = __expf(s[qf][kt][2] - mold[qf]), p3 = __expf(s[qf][kt][3] - mold[qf]);
        lpart[qf] += (p0 + p1) + (p2 + p3);
        pk[kt*2+0] = (unsigned)f2bf(p0) | ((unsigned)f2bf(p1) << 16);
        pk[kt*2+1] = (unsigned)f2bf(p2) | ((unsigned)f2bf(p3) << 16);
      }
      // pa0 from pk[0..3]
      unsigned lo0 = __shfl(pk[0], srcA, 64), lo1 = __shfl(pk[1], srcA, 64);
      unsigned lo2 = __shfl(pk[2], srcA, 64), lo3 = __shfl(pk[3], srcA, 64);
      unsigned hi0 = __shfl(pk[0], srcB, 64), hi1 = __shfl(pk[1], srcB, 64);
      unsigned hi2 = __shfl(pk[2], srcB, 64), hi3 = __shfl(pk[3], srcB, 64);
      union { unsigned u[4]; bf16x8 v; } A0, A1;
      A0.u[0] = sello ? lo0 : lo2;  A0.u[1] = sello ? lo1 : lo3;
      A0.u[2] = sello ? hi0 : hi2;  A0.u[3] = sello ? hi1 : hi3;
      // pa1 from pk[4..7]
      unsigned l4 = __shfl(pk[4], srcA, 64), l5 = __shfl(pk[5], srcA, 64);
      unsigned l6 = __shfl(pk[6], srcA, 64), l7 = __shfl(pk[7], srcA, 64);
      unsigned h4 = __shfl(pk[4], srcB, 64), h5 = __shfl(pk[5], srcB, 64);
      unsigned h6 = __shfl(pk[6], srcB, 64), h7 = __shfl(pk[7], srcB, 64);
      A1.u[0] = sello ? l4 : l6;  A1.u[1] = sello ? l5 : l7;
      A1.u[2] = sello ? h4 : h6;  A1.u[3] = sello ? h5 : h7;
      // PV: 8 MFMAs, A-frags straight from registers
#pragma unroll
      for (int db = 0; db < 4; ++db) {
        bf16x8 vf0 = *(const bf16x8*)&Vs[bb][db*16 + r16][ko0];
        bf16x8 vf1 = *(const bf16x8*)&Vs[bb][db*16 + r16][ko1];
        acc[qf][db] = __builtin_amdgcn_mfma_f32_16x16x32_bf16(A0.v, vf0, acc[qf][db], 0, 0, 0);
        acc[qf][db] = __builtin_amdgcn_mfma_f32_16x16x32_bf16(A1.v, vf1, acc[qf][db], 0, 0, 0);
      }
    }
    __syncthreads();   // drains vmcnt (stage) + lgkm; next tile ready
  }

  // epilogue: reduce partial denominators across the k-lane groups, normalize
#pragma unroll
  for (int qf = 0; qf < 2; ++qf) {
    float lp = lpart[qf];
    lp += __shfl_xor(lp, 16, 64);
    lp += __shfl_xor(lp, 32, 64);
    float linv = 1.0f / lp;
    float invq[4];
#pragma unroll
    for (int jj = 0; jj < 4; ++jj) invq[jj] = __shfl(linv, kg*4 + jj, 64);
#pragma unroll
    for (int jj = 0; jj < 4; ++jj)
#pragma unroll
      for (int db = 0; db < 4; ++db)
        X[((size_t)b*T_ + q0w + qf*16 + kg*4 + jj)*D_ + h*DK_ + db*16 + r16] =
            f2bf(acc[qf][db][jj] * invq[jj]);
  }
}

// ---------------- fallback attention (fp32 qa direct, block barriers) ------
__global__ __launch_bounds__(256) void attn_fused(
    const unsigned short* __restrict__ Q, const unsigned short* __restrict__ K,
    const unsigned short* __restrict__ Vt, const float* __restrict__ qa,
    const int* __restrict__ mask, unsigned short* __restrict__ X) {
  int bid = blockIdx.x;
  int qt = bid & 15, h = (bid >> 4) & 15, b = bid >> 8;
  int w = threadIdx.x >> 6, lane = threadIdx.x & 63;
  int r16 = lane & 15, kg = lane >> 4;
  int q0 = qt*64 + w*16;
  int bh = b*H_ + h;

  __shared__ unsigned short P[4][16][72];

  const unsigned short* qrow = Q + ((size_t)b*T_ + q0 + r16)*D_ + h*DK_ + kg*8;
  bf16x8 qf0 = *(const bf16x8*)qrow;
  bf16x8 qf1 = *(const bf16x8*)(qrow + 32);

  f32x4 acc[4];
#pragma unroll
  for (int db = 0; db < 4; ++db) acc[db] = (f32x4){0.f,0.f,0.f,0.f};
  float mrow[4], lrow[4];
#pragma unroll
  for (int jj = 0; jj < 4; ++jj) { mrow[jj] = -3e38f; lrow[jj] = 0.f; }

  const int* mptr = mask + b*T_;
  const unsigned short* Kbase = K + ((size_t)b*T_)*D_ + h*DK_;
  const unsigned short* Vbase = Vt + ((size_t)bh*DK_)*T_;
  const float* qabase = qa + ((size_t)(b*T_ + q0 + kg*4))*T_*C_ + h;

  for (int k0 = 0; k0 < T_; k0 += 64) {
    f32x4 s[4];
#pragma unroll
    for (int kt = 0; kt < 4; ++kt) {
      const unsigned short* krow = Kbase + (size_t)(k0 + kt*16 + r16)*D_ + kg*8;
      f32x4 z = (f32x4){0.f,0.f,0.f,0.f};
      z = __builtin_amdgcn_mfma_f32_16x16x32_bf16(qf0, *(const bf16x8*)krow,        z, 0, 0, 0);
      z = __builtin_amdgcn_mfma_f32_16x16x32_bf16(qf1, *(const bf16x8*)(krow + 32), z, 0, 0, 0);
      s[kt] = z;
    }
    int mk[4];
#pragma unroll
    for (int kt = 0; kt < 4; ++kt) mk[kt] = mptr[k0 + kt*16 + r16];
    if (h < C_) {
#pragma unroll
      for (int kt = 0; kt < 4; ++kt)
#pragma unroll
        for (int jj = 0; jj < 4; ++jj) {
          float bb = qabase[(size_t)jj*T_*C_ + (size_t)(k0 + kt*16 + r16)*C_];
          s[kt][jj] = s[kt][jj]*0.125f + 5.0f*bb;
        }
    } else {
#pragma unroll
      for (int kt = 0; kt < 4; ++kt)
#pragma unroll
        for (int jj = 0; jj < 4; ++jj) s[kt][jj] *= 0.125f;
    }
#pragma unroll
    for (int kt = 0; kt < 4; ++kt)
#pragma unroll
      for (int jj = 0; jj < 4; ++jj)
        if (mk[kt] == 0) s[kt][jj] = -1e9f;

#pragma unroll
    for (int jj = 0; jj < 4; ++jj) {
      float v = fmaxf(fmaxf(s[0][jj], s[1][jj]), fmaxf(s[2][jj], s[3][jj]));
#pragma unroll
      for (int d = 1; d < 16; d <<= 1) v = fmaxf(v, __shfl_xor(v, d, 64));
      float mnew = fmaxf(mrow[jj], v);
      float sc = __expf(mrow[jj] - mnew);
      mrow[jj] = mnew;
      lrow[jj] *= sc;
#pragma unroll
      for (int db = 0; db < 4; ++db) acc[db][jj] *= sc;
      float rs = 0.f;
#pragma unroll
      for (int kt = 0; kt < 4; ++kt) {
        float p = __expf(s[kt][jj] - mnew);
        rs += p;
        P[w][kg*4 + jj][kt*16 + r16] = f2bf(p);
      }
#pragma unroll
      for (int d = 1; d < 16; d <<= 1) rs += __shfl_xor(rs, d, 64);
      lrow[jj] += rs;
    }
    __syncthreads();

    bf16x8 pa0 = *(const bf16x8*)&P[w][r16][kg*8];
    bf16x8 pa1 = *(const bf16x8*)&P[w][r16][32 + kg*8];
#pragma unroll
    for (int db = 0; db < 4; ++db) {
      const unsigned short* vr = Vbase + (size_t)(db*16 + r16)*T_ + k0 + kg*8;
      acc[db] = __builtin_amdgcn_mfma_f32_16x16x32_bf16(pa0, *(const bf16x8*)vr,        acc[db], 0, 0, 0);
      acc[db] = __builtin_amdgcn_mfma_f32_16x16x32_bf16(pa1, *(const bf16x8*)(vr + 32), acc[db], 0, 0, 0);
    }
  }

  float inv[4];
#pragma unroll
  for (int jj = 0; jj < 4; ++jj) inv[jj] = 1.0f / lrow[jj];
#pragma unroll
  for (int jj = 0; jj < 4; ++jj)
#pragma unroll
    for (int db = 0; db < 4; ++db)
      X[((size_t)b*T_ + q0 + kg*4 + jj)*D_ + h*DK_ + db*16 + r16] =
          f2bf(acc[db][jj] * inv[jj]);
}

extern "C" void kernel_launch(void* const* d_in, const int* in_sizes, int n_in,
                              void* d_out, int out_size, void* d_ws, size_t ws_size,
                              hipStream_t stream) {
  const float* qa    = (const float*)d_in[0];
  const float* query = (const float*)d_in[1];
  const float* key   = (const float*)d_in[2];
  const float* value = (const float*)d_in[3];
  const float* Wq = (const float*)d_in[4];
  const float* bq = (const float*)d_in[5];
  const float* Wk = (const float*)d_in[6];
  const float* bk = (const float*)d_in[7];
  const float* Wv = (const float*)d_in[8];
  const float* bv = (const float*)d_in[9];
  const float* Wo = (const float*)d_in[10];
  const float* bo = (const float*)d_in[11];
  const int* mask = (const int*)d_in[12];

  const size_t ND = (size_t)N_ * D_;
  const size_t DD = (size_t)D_ * D_;
  const size_t QAT = (size_t)B_ * C_ * T_ * T_;
  unsigned short* Qws = (unsigned short*)d_ws;
  unsigned short* Kws = Qws + ND;
  unsigned short* Vws = Kws + ND;
  unsigned short* Xws = Vws + ND;
  unsigned short* qbf = Xws + ND;     // doubles as Vt after the Q GEMM
  unsigned short* kbf = qbf + ND;
  unsigned short* vbf = kbf + ND;
  unsigned short* wqbf = vbf + ND;
  unsigned short* wkbf = wqbf + DD;
  unsigned short* wvbf = wkbf + DD;
  unsigned short* wobf = wvbf + DD;
  unsigned short* qatws = wobf + DD;  // fp16 qa_t [B][C][T][T]
  unsigned short* Vtws = qbf;

  bool fast = ws_size >= (7*ND + 4*DD + QAT) * sizeof(unsigned short);

  dim3 blk(256);
  cvt_qkv<<<3072, blk, 0, stream>>>(query, key, value, qbf, kbf, vbf, (int)(ND/4));
  cvt_w<<<1024, blk, 0, stream>>>(Wq, Wk, Wv, Wo, wqbf, wkbf, wvbf, wobf, (int)(DD/4));

  gemm_qkv<<<3*512, blk, 0, stream>>>(qbf, kbf, vbf, wqbf, wkbf, wvbf,
                                      bq, bk, bv, Qws, Kws, Vws);

  if (fast) {
    tv_tqa<<<2048 + 8192, blk, 0, stream>>>(Vws, Vtws, qa, qatws);
    attn5s<<<B_*H_*(T_/128), blk, 0, stream>>>(Qws, Kws, Vtws, qatws, mask, Xws);
  } else {
    transposeV<<<B_*H_*(T_/64), blk, 0, stream>>>(Vws, Vtws);
    attn_fused<<<B_*H_*(T_/64), blk, 0, stream>>>(Qws, Kws, Vtws, qa, mask, Xws);
  }

  gemm_lds<true><<<512, blk, 0, stream>>>(Xws, wobf, bo, (float*)d_out);
}

// Round 19
// 321.587 us; speedup vs baseline: 1.4498x; 1.4498x over previous
//
#include <hip/hip_runtime.h>

#define B_  8
#define T_  1024
#define D_  1024
#define H_  16
#define DK_ 64
#define C_  8
#define N_  (B_*T_)   // 8192 rows

typedef __attribute__((ext_vector_type(8))) short bf16x8;
typedef __attribute__((ext_vector_type(4))) float f32x4;
typedef __attribute__((ext_vector_type(8))) unsigned short u16x8;
typedef __attribute__((ext_vector_type(4))) unsigned short u16x4;

__device__ __forceinline__ float bf2f(unsigned short u) {
  union { unsigned int i; float f; } x; x.i = ((unsigned int)u) << 16; return x.f;
}
__device__ __forceinline__ unsigned short f2bf(float f) {
  union { float f; unsigned int i; } x; x.f = f;
  unsigned int r = (x.i + 0x7fffu + ((x.i >> 16) & 1u)) >> 16;
  return (unsigned short)r;
}
__device__ __forceinline__ unsigned short f2h(float f) {
  union { _Float16 h; unsigned short u; } x; x.h = (_Float16)f; return x.u;
}
__device__ __forceinline__ float h2f(unsigned short u) {
  union { _Float16 h; unsigned short u; } x; x.u = u; return (float)x.h;
}

// async global->LDS, 16B per lane. LDS dest is wave-uniform base + lane*16.
__device__ __forceinline__ void gl_lds16(const unsigned short* g, unsigned short* l) {
  __builtin_amdgcn_global_load_lds(
      (const __attribute__((address_space(1))) unsigned int*)g,
      (__attribute__((address_space(3))) unsigned int*)l,
      16, 0, 0);
}

// ---- fused fp32->bf16 for query/key/value (3 segments, 1 launch) ----------
__global__ __launch_bounds__(256) void cvt_qkv(
    const float* __restrict__ q, const float* __restrict__ k,
    const float* __restrict__ v, unsigned short* __restrict__ qo,
    unsigned short* __restrict__ ko, unsigned short* __restrict__ vo, int n4) {
  int seg = blockIdx.x >> 10;              // 1024 blocks per segment
  int bid = blockIdx.x & 1023;
  const float* in = (seg == 0) ? q : (seg == 1) ? k : v;
  unsigned short* out = (seg == 0) ? qo : (seg == 1) ? ko : vo;
  int tid = bid * blockDim.x + threadIdx.x;
  int stride = 1024 * 256;
  const float4* in4 = (const float4*)in;
  u16x4* out4 = (u16x4*)out;
  for (int i = tid; i < n4; i += stride) {
    float4 vv = in4[i];
    u16x4 o = { f2bf(vv.x), f2bf(vv.y), f2bf(vv.z), f2bf(vv.w) };
    out4[i] = o;
  }
}

// ---- fused fp32->bf16 for the 4 weight matrices (1 launch) ----------------
__global__ __launch_bounds__(256) void cvt_w(
    const float* __restrict__ w0, const float* __restrict__ w1,
    const float* __restrict__ w2, const float* __restrict__ w3,
    unsigned short* __restrict__ o0, unsigned short* __restrict__ o1,
    unsigned short* __restrict__ o2, unsigned short* __restrict__ o3, int n4) {
  int seg = blockIdx.x >> 8;               // 256 blocks per segment
  int bid = blockIdx.x & 255;
  const float* in = (seg == 0) ? w0 : (seg == 1) ? w1 : (seg == 2) ? w2 : w3;
  unsigned short* out = (seg == 0) ? o0 : (seg == 1) ? o1 : (seg == 2) ? o2 : o3;
  int tid = bid * blockDim.x + threadIdx.x;
  int stride = 256 * 256;
  const float4* in4 = (const float4*)in;
  u16x4* out4 = (u16x4*)out;
  for (int i = tid; i < n4; i += stride) {
    float4 vv = in4[i];
    u16x4 o = { f2bf(vv.x), f2bf(vv.y), f2bf(vv.z), f2bf(vv.w) };
    out4[i] = o;
  }
}

// ---- transposeQa body: qa [B][T][T][C] fp32 -> qat [B][C][T][T] fp16 ------
__device__ __forceinline__ void tqa_body(
    int bid, const float* __restrict__ qa, unsigned short* __restrict__ qat,
    float (*L)[132]) {
  int b = bid >> 10, q = bid & 1023;
  int t = threadIdx.x;
  const float* src = qa + ((size_t)(b*T_ + q))*T_*C_;
  for (int ch = 0; ch < 8; ++ch) {
    int k0 = ch*128;
    float4 v = *(const float4*)(src + (size_t)(k0 + (t>>1))*C_ + (t&1)*4);
    int c4 = (t&1)*4, kk = t>>1;
    L[c4+0][kk] = v.x; L[c4+1][kk] = v.y; L[c4+2][kk] = v.z; L[c4+3][kk] = v.w;
    __syncthreads();
    int c = t >> 5, kk2 = (t&31)*4;
    float4 p = *(const float4*)&L[c][kk2];
    u16x4 o = { f2h(p.x), f2h(p.y), f2h(p.z), f2h(p.w) };
    *(u16x4*)(qat + ((size_t)(b*C_ + c)*T_ + q)*T_ + k0 + kk2) = o;
    __syncthreads();
  }
}

// ---- transposeV body: V [b*T+t][h*64+d] -> Vt [(b*H+h)*64+d][T] -----------
__device__ __forceinline__ void tv_body(
    int bid, const unsigned short* __restrict__ V, unsigned short* __restrict__ Vt,
    unsigned short (*L)[72]) {
  int tt = bid & 15;
  int bh = bid >> 4;               // 0..127
  int b = bh >> 4, h = bh & 15;
  int r  = threadIdx.x >> 3;       // 0..31
  int c8 = (threadIdx.x & 7) * 8;
  const unsigned short* src = V + ((size_t)(b*T_ + tt*64))*D_ + h*64;
#pragma unroll
  for (int p = 0; p < 2; ++p) {
    int rr = r + p*32;
    u16x8 v = *(const u16x8*)(src + (size_t)rr*D_ + c8);
    *(u16x8*)&L[rr][c8] = v;
  }
  __syncthreads();
  unsigned short* dst = Vt + ((size_t)bh*64)*T_ + tt*64;
#pragma unroll
  for (int p = 0; p < 2; ++p) {
    int d = r + p*32;
    u16x8 o;
#pragma unroll
    for (int i = 0; i < 8; ++i) o[i] = L[c8 + i][d];
    *(u16x8*)(dst + (size_t)d*T_ + c8) = o;
  }
}

// ---- fused transposeV + transposeQa (both pure-BW streamers, same regime) -
__global__ __launch_bounds__(256) void tv_tqa(
    const unsigned short* __restrict__ V, unsigned short* __restrict__ Vt,
    const float* __restrict__ qa, unsigned short* __restrict__ qat) {
  __shared__ __align__(16) unsigned char smem[9216];  // union of both bodies
  if (blockIdx.x < 2048) {
    tv_body(blockIdx.x, V, Vt, (unsigned short(*)[72])smem);
  } else {
    tqa_body(blockIdx.x - 2048, qa, qat, (float(*)[132])smem);
  }
}

// standalone versions (fallback path)
__global__ __launch_bounds__(256) void transposeQa(
    const float* __restrict__ qa, unsigned short* __restrict__ qat) {
  __shared__ float L[8][132];
  tqa_body(blockIdx.x, qa, qat, L);
}
__global__ __launch_bounds__(256) void transposeV(
    const unsigned short* __restrict__ V, unsigned short* __restrict__ Vt) {
  __shared__ unsigned short L[64][72];
  tv_body(blockIdx.x, V, Vt, L);
}

// ---------------- m97-structure GEMM body: 128x128 tile, BK=32, 4 waves ----
template <bool OUT_F32>
__device__ __forceinline__ void gemm_body(
    int blockid, const unsigned short* __restrict__ X,
    const unsigned short* __restrict__ W, const float* __restrict__ bias,
    void* __restrict__ Yv, unsigned short* As, unsigned short* Bs) {
  int orig = (blockid & 7) * 64 + (blockid >> 3);   // bijective (512%8==0)
  int bm = orig >> 3, bn = orig & 7;
  int t = threadIdx.x, lane = t & 63, w = t >> 6;
  int wr = w >> 1, wc = w & 1;
  int r16 = lane & 15, kg = lane >> 4;

  int srow0 = lane >> 2;
  int scol  = (lane & 3) * 8;
  const unsigned short* Ab = X + (size_t)(bm*128)*D_ + scol;
  const unsigned short* Bb = W + (size_t)(bn*128)*D_ + scol;

  f32x4 acc[4][4];
#pragma unroll
  for (int m = 0; m < 4; ++m)
#pragma unroll
    for (int n = 0; n < 4; ++n) acc[m][n] = (f32x4){0.f,0.f,0.f,0.f};

  for (int k0 = 0; k0 < D_; k0 += 32) {
    __syncthreads();
#pragma unroll
    for (int c = 0; c < 2; ++c) {
      int cidx = w*2 + c;
      int row = cidx*16 + srow0;
      gl_lds16(Ab + (size_t)row*D_ + k0, As + cidx*512);
      gl_lds16(Bb + (size_t)row*D_ + k0, Bs + cidx*512);
    }
    __syncthreads();

    bf16x8 a[4], bb[4];
#pragma unroll
    for (int m = 0; m < 4; ++m)
      a[m] = *(const bf16x8*)(As + (wr*64 + m*16 + r16)*32 + kg*8);
#pragma unroll
    for (int n = 0; n < 4; ++n)
      bb[n] = *(const bf16x8*)(Bs + (wc*64 + n*16 + r16)*32 + kg*8);
#pragma unroll
    for (int m = 0; m < 4; ++m)
#pragma unroll
      for (int n = 0; n < 4; ++n)
        acc[m][n] = __builtin_amdgcn_mfma_f32_16x16x32_bf16(a[m], bb[n], acc[m][n], 0, 0, 0);
  }

#pragma unroll
  for (int n = 0; n < 4; ++n) {
    int col = bn*128 + wc*64 + n*16 + r16;
    float bv = bias[col];
#pragma unroll
    for (int m = 0; m < 4; ++m) {
      int row0 = bm*128 + wr*64 + m*16 + kg*4;
#pragma unroll
      for (int jj = 0; jj < 4; ++jj) {
        float rv = acc[m][n][jj] + bv;
        if constexpr (OUT_F32)
          ((float*)Yv)[(size_t)(row0 + jj)*D_ + col] = rv;
        else
          ((unsigned short*)Yv)[(size_t)(row0 + jj)*D_ + col] = f2bf(rv);
      }
    }
  }
}

// single GEMM (used for the output projection)
template <bool OUT_F32>
__global__ __launch_bounds__(256) void gemm_lds(
    const unsigned short* __restrict__ X, const unsigned short* __restrict__ W,
    const float* __restrict__ bias, void* __restrict__ Yv) {
  __shared__ __align__(16) unsigned short As[128*32];
  __shared__ __align__(16) unsigned short Bs[128*32];
  gemm_body<OUT_F32>(blockIdx.x, X, W, bias, Yv, As, Bs);
}

// fused Q/K/V projections: grid = 3*512, segment-decoded
__global__ __launch_bounds__(256) void gemm_qkv(
    const unsigned short* __restrict__ Xq, const unsigned short* __restrict__ Xk,
    const unsigned short* __restrict__ Xv,
    const unsigned short* __restrict__ Wq2, const unsigned short* __restrict__ Wk2,
    const unsigned short* __restrict__ Wv2,
    const float* __restrict__ bq2, const float* __restrict__ bk2,
    const float* __restrict__ bv2,
    unsigned short* __restrict__ Yq, unsigned short* __restrict__ Yk,
    unsigned short* __restrict__ Yv2) {
  __shared__ __align__(16) unsigned short As[128*32];
  __shared__ __align__(16) unsigned short Bs[128*32];
  int seg = blockIdx.x >> 9, inner = blockIdx.x & 511;
  const unsigned short* X = (seg == 0) ? Xq : (seg == 1) ? Xk : Xv;
  const unsigned short* W = (seg == 0) ? Wq2 : (seg == 1) ? Wk2 : Wv2;
  const float* bias = (seg == 0) ? bq2 : (seg == 1) ? bk2 : bv2;
  unsigned short* Y = (seg == 0) ? Yq : (seg == 1) ? Yk : Yv2;
  gemm_body<false>(inner, X, W, bias, Y, As, Bs);
}

// ---------------- attn4b (proven ~128us): single-fence + deferred lsum -----
// block = (b,h,128 q-rows); wave w owns q = q0w..q0w+31 (2 q-frags of 16).
// K/V tiles double-buffered LDS (both-sides swizzle); swapped QK^T; per-qf
// P buffers so ONE lgkm fence serves both PV blocks; lsum kept per-lane
// partial (reduced in epilogue); rescale skipped unless row-max grew > 8.
// FINAL: occ-3 / ~84 VGPR is this kernel's structural optimum. All register-
// widening edits spill (R10 qa-prefetch, R12 vf-hoist, R16 occ-4, R18
// shuffle-P); scheduling edits neutral (R15). Do not modify.
__global__ __launch_bounds__(256, 3) void attn4b(
    const unsigned short* __restrict__ Q, const unsigned short* __restrict__ K,
    const unsigned short* __restrict__ Vt, const unsigned short* __restrict__ qat,
    const int* __restrict__ mask, unsigned short* __restrict__ X) {
  int swzid = ((blockIdx.x & 7) << 7) | (blockIdx.x >> 3);  // XCD-chunked, 1024
  int qt = swzid & 7, h = (swzid >> 3) & 15, b = swzid >> 7;
  int w = threadIdx.x >> 6, lane = threadIdx.x & 63;
  int r16 = lane & 15, kg = lane >> 4;
  int q0w = qt*128 + w*32;
  int bh = b*H_ + h;

  __shared__ unsigned short Ks[2][64][64];    // 16 KB
  __shared__ unsigned short Vs[2][64][64];    // 16 KB
  __shared__ unsigned int  P32[4][2][16][32]; // 16 KB, per (wave, qf)

  int rl = lane >> 3;
  int eo = ((lane & 7) * 8) ^ (rl << 3);     // swizzled elem offset in row
  const unsigned short* Kb = K + ((size_t)b*T_)*D_ + h*DK_;
  const unsigned short* Vb = Vt + ((size_t)bh*DK_)*T_;

  int sw16 = (r16 & 7) << 4;
  int ko0 = ((kg*16 +  0) ^ sw16) >> 1;      // elem offset, half 0
  int ko1 = ((kg*16 + 64) ^ sw16) >> 1;      // elem offset, half 1
  int sw32 = (r16 & 7) << 2;                 // word swizzle for P

  bf16x8 qfr[2][2];
#pragma unroll
  for (int qf = 0; qf < 2; ++qf) {
    const unsigned short* qrow = Q + ((size_t)b*T_ + q0w + qf*16 + r16)*D_ + h*DK_ + kg*8;
    qfr[qf][0] = *(const bf16x8*)qrow;
    qfr[qf][1] = *(const bf16x8*)(qrow + 32);
  }

  f32x4 acc[2][4];
#pragma unroll
  for (int qf = 0; qf < 2; ++qf)
#pragma unroll
    for (int db = 0; db < 4; ++db) acc[qf][db] = (f32x4){0.f,0.f,0.f,0.f};
  float mold[2] = {-3e38f, -3e38f};
  float lpart[2] = {0.f, 0.f};    // per-lane partial denominator (16 k each)

  const int* mrow = mask + b*T_;
  const unsigned short* qab0 = qat + ((size_t)((b*C_ + h)*T_) + q0w + r16)*T_;

  // prologue: stage tile 0 into buffer 0
#pragma unroll
  for (int c = 0; c < 2; ++c) {
    int cc = w*2 + c;
    gl_lds16(Kb + (size_t)(cc*8 + rl)*D_ + eo, &Ks[0][cc*8][0]);
    gl_lds16(Vb + (size_t)(cc*8 + rl)*T_ + eo, &Vs[0][cc*8][0]);
  }
  __syncthreads();

  for (int t = 0; t < 16; ++t) {
    int k0 = t*64, bb = t & 1;
    // ---- stage next tile into other buffer ----
    if (t < 15) {
      int kn = k0 + 64, nb = bb ^ 1;
#pragma unroll
      for (int c = 0; c < 2; ++c) {
        int cc = w*2 + c;
        gl_lds16(Kb + (size_t)(kn + cc*8 + rl)*D_ + eo, &Ks[nb][cc*8][0]);
        gl_lds16(Vb + (size_t)(cc*8 + rl)*T_ + kn + eo, &Vs[nb][cc*8][0]);
      }
    }
    // ---- qa + mask loads ----
    u16x4 qv[2][4];
    if (h < C_) {
#pragma unroll
      for (int qf = 0; qf < 2; ++qf)
#pragma unroll
        for (int kt = 0; kt < 4; ++kt)
          qv[qf][kt] = *(const u16x4*)(qab0 + (size_t)qf*16*T_ + k0 + kt*16 + kg*4);
    }
    int mk = mrow[k0 + lane];
    unsigned long long bits = __ballot(mk != 0);

    // ---- QK^T from LDS: s[qf][kt], rows=k cols=q ----
    f32x4 s[2][4];
#pragma unroll
    for (int kt = 0; kt < 4; ++kt) {
      bf16x8 kf0 = *(const bf16x8*)&Ks[bb][kt*16 + r16][ko0];
      bf16x8 kf1 = *(const bf16x8*)&Ks[bb][kt*16 + r16][ko1];
#pragma unroll
      for (int qf = 0; qf < 2; ++qf) {
        f32x4 z = (f32x4){0.f,0.f,0.f,0.f};
        z = __builtin_amdgcn_mfma_f32_16x16x32_bf16(kf0, qfr[qf][0], z, 0, 0, 0);
        z = __builtin_amdgcn_mfma_f32_16x16x32_bf16(kf1, qfr[qf][1], z, 0, 0, 0);
        s[qf][kt] = z;
      }
    }

    // ---- scale + bias + mask; row-max per q-frag (2 shfl each) ----
    float pmaxq[2];
#pragma unroll
    for (int qf = 0; qf < 2; ++qf) {
      float pmax = -3e38f;
#pragma unroll
      for (int kt = 0; kt < 4; ++kt)
#pragma unroll
        for (int jj = 0; jj < 4; ++jj) {
          float v = s[qf][kt][jj] * 0.125f;
          if (h < C_) v += 5.0f * h2f(qv[qf][kt][jj]);
          int idx = kt*16 + kg*4 + jj;
          v = ((bits >> idx) & 1ULL) ? v : -1e9f;
          s[qf][kt][jj] = v;
          pmax = fmaxf(pmax, v);
        }
      pmax = fmaxf(pmax, __shfl_xor(pmax, 16, 64));
      pmax = fmaxf(pmax, __shfl_xor(pmax, 32, 64));
      pmaxq[qf] = pmax;
    }
    // ---- defer-max: rescale only when a row's max grew by > 8 ----
    if (!__all(pmaxq[0] - mold[0] <= 8.0f && pmaxq[1] - mold[1] <= 8.0f)) {
#pragma unroll
      for (int qf = 0; qf < 2; ++qf) {
        float mnew = fmaxf(mold[qf], pmaxq[qf]);
        float sc = __expf(mold[qf] - mnew);
        mold[qf] = mnew;
        lpart[qf] *= sc;
        float scq[4];
#pragma unroll
        for (int jj = 0; jj < 4; ++jj) scq[jj] = __shfl(sc, kg*4 + jj, 64);
#pragma unroll
        for (int db = 0; db < 4; ++db)
#pragma unroll
          for (int jj = 0; jj < 4; ++jj) acc[qf][db][jj] *= scq[jj];
      }
    }
    // ---- exp + pack + P write, both q-frags; ONE fence ----
#pragma unroll
    for (int qf = 0; qf < 2; ++qf) {
      unsigned int pk[8];
#pragma unroll
      for (int kt = 0; kt < 4; ++kt) {
        float p0 = __expf(s[qf][kt][0] - mold[qf]), p1 = __expf(s[qf][kt][1] - mold[qf]);
        float p2 = __expf(s[qf][kt][2] - mold[qf]), p3 = __expf(s[qf][kt][3] - mold[qf]);
        lpart[qf] += (p0 + p1) + (p2 + p3);
        pk[kt*2+0] = (unsigned)f2bf(p0) | ((unsigned)f2bf(p1) << 16);
        pk[kt*2+1] = (unsigned)f2bf(p2) | ((unsigned)f2bf(p3) << 16);
      }
#pragma unroll
      for (int kt = 0; kt < 4; ++kt)
        *(uint2*)&P32[w][qf][r16][(kt*8 + kg*2) ^ sw32] =
            make_uint2(pk[kt*2], pk[kt*2+1]);
    }
    asm volatile("s_waitcnt lgkmcnt(0)" ::: "memory");
    __builtin_amdgcn_sched_barrier(0);
    // ---- PV for both q-frags (16 contiguous MFMAs) ----
#pragma unroll
    for (int qf = 0; qf < 2; ++qf) {
      bf16x8 pa0 = *(const bf16x8*)&P32[w][qf][r16][(kg*4) ^ sw32];
      bf16x8 pa1 = *(const bf16x8*)&P32[w][qf][r16][(16 + kg*4) ^ sw32];
#pragma unroll
      for (int db = 0; db < 4; ++db) {
        bf16x8 vf0 = *(const bf16x8*)&Vs[bb][db*16 + r16][ko0];
        bf16x8 vf1 = *(const bf16x8*)&Vs[bb][db*16 + r16][ko1];
        acc[qf][db] = __builtin_amdgcn_mfma_f32_16x16x32_bf16(pa0, vf0, acc[qf][db], 0, 0, 0);
        acc[qf][db] = __builtin_amdgcn_mfma_f32_16x16x32_bf16(pa1, vf1, acc[qf][db], 0, 0, 0);
      }
    }
    __syncthreads();   // drains vmcnt (stage) + lgkm; next tile ready
  }

  // epilogue: reduce partial denominators across the 4 kg-lanes, normalize
#pragma unroll
  for (int qf = 0; qf < 2; ++qf) {
    float lp = lpart[qf];
    lp += __shfl_xor(lp, 16, 64);
    lp += __shfl_xor(lp, 32, 64);
    float linv = 1.0f / lp;
    float invq[4];
#pragma unroll
    for (int jj = 0; jj < 4; ++jj) invq[jj] = __shfl(linv, kg*4 + jj, 64);
#pragma unroll
    for (int jj = 0; jj < 4; ++jj)
#pragma unroll
      for (int db = 0; db < 4; ++db)
        X[((size_t)b*T_ + q0w + qf*16 + kg*4 + jj)*D_ + h*DK_ + db*16 + r16] =
            f2bf(acc[qf][db][jj] * invq[jj]);
  }
}

// ---------------- fallback attention (fp32 qa direct, block barriers) ------
__global__ __launch_bounds__(256) void attn_fused(
    const unsigned short* __restrict__ Q, const unsigned short* __restrict__ K,
    const unsigned short* __restrict__ Vt, const float* __restrict__ qa,
    const int* __restrict__ mask, unsigned short* __restrict__ X) {
  int bid = blockIdx.x;
  int qt = bid & 15, h = (bid >> 4) & 15, b = bid >> 8;
  int w = threadIdx.x >> 6, lane = threadIdx.x & 63;
  int r16 = lane & 15, kg = lane >> 4;
  int q0 = qt*64 + w*16;
  int bh = b*H_ + h;

  __shared__ unsigned short P[4][16][72];

  const unsigned short* qrow = Q + ((size_t)b*T_ + q0 + r16)*D_ + h*DK_ + kg*8;
  bf16x8 qf0 = *(const bf16x8*)qrow;
  bf16x8 qf1 = *(const bf16x8*)(qrow + 32);

  f32x4 acc[4];
#pragma unroll
  for (int db = 0; db < 4; ++db) acc[db] = (f32x4){0.f,0.f,0.f,0.f};
  float mrow[4], lrow[4];
#pragma unroll
  for (int jj = 0; jj < 4; ++jj) { mrow[jj] = -3e38f; lrow[jj] = 0.f; }

  const int* mptr = mask + b*T_;
  const unsigned short* Kbase = K + ((size_t)b*T_)*D_ + h*DK_;
  const unsigned short* Vbase = Vt + ((size_t)bh*DK_)*T_;
  const float* qabase = qa + ((size_t)(b*T_ + q0 + kg*4))*T_*C_ + h;

  for (int k0 = 0; k0 < T_; k0 += 64) {
    f32x4 s[4];
#pragma unroll
    for (int kt = 0; kt < 4; ++kt) {
      const unsigned short* krow = Kbase + (size_t)(k0 + kt*16 + r16)*D_ + kg*8;
      f32x4 z = (f32x4){0.f,0.f,0.f,0.f};
      z = __builtin_amdgcn_mfma_f32_16x16x32_bf16(qf0, *(const bf16x8*)krow,        z, 0, 0, 0);
      z = __builtin_amdgcn_mfma_f32_16x16x32_bf16(qf1, *(const bf16x8*)(krow + 32), z, 0, 0, 0);
      s[kt] = z;
    }
    int mk[4];
#pragma unroll
    for (int kt = 0; kt < 4; ++kt) mk[kt] = mptr[k0 + kt*16 + r16];
    if (h < C_) {
#pragma unroll
      for (int kt = 0; kt < 4; ++kt)
#pragma unroll
        for (int jj = 0; jj < 4; ++jj) {
          float bb = qabase[(size_t)jj*T_*C_ + (size_t)(k0 + kt*16 + r16)*C_];
          s[kt][jj] = s[kt][jj]*0.125f + 5.0f*bb;
        }
    } else {
#pragma unroll
      for (int kt = 0; kt < 4; ++kt)
#pragma unroll
        for (int jj = 0; jj < 4; ++jj) s[kt][jj] *= 0.125f;
    }
#pragma unroll
    for (int kt = 0; kt < 4; ++kt)
#pragma unroll
      for (int jj = 0; jj < 4; ++jj)
        if (mk[kt] == 0) s[kt][jj] = -1e9f;

#pragma unroll
    for (int jj = 0; jj < 4; ++jj) {
      float v = fmaxf(fmaxf(s[0][jj], s[1][jj]), fmaxf(s[2][jj], s[3][jj]));
#pragma unroll
      for (int d = 1; d < 16; d <<= 1) v = fmaxf(v, __shfl_xor(v, d, 64));
      float mnew = fmaxf(mrow[jj], v);
      float sc = __expf(mrow[jj] - mnew);
      mrow[jj] = mnew;
      lrow[jj] *= sc;
#pragma unroll
      for (int db = 0; db < 4; ++db) acc[db][jj] *= sc;
      float rs = 0.f;
#pragma unroll
      for (int kt = 0; kt < 4; ++kt) {
        float p = __expf(s[kt][jj] - mnew);
        rs += p;
        P[w][kg*4 + jj][kt*16 + r16] = f2bf(p);
      }
#pragma unroll
      for (int d = 1; d < 16; d <<= 1) rs += __shfl_xor(rs, d, 64);
      lrow[jj] += rs;
    }
    __syncthreads();

    bf16x8 pa0 = *(const bf16x8*)&P[w][r16][kg*8];
    bf16x8 pa1 = *(const bf16x8*)&P[w][r16][32 + kg*8];
#pragma unroll
    for (int db = 0; db < 4; ++db) {
      const unsigned short* vr = Vbase + (size_t)(db*16 + r16)*T_ + k0 + kg*8;
      acc[db] = __builtin_amdgcn_mfma_f32_16x16x32_bf16(pa0, *(const bf16x8*)vr,        acc[db], 0, 0, 0);
      acc[db] = __builtin_amdgcn_mfma_f32_16x16x32_bf16(pa1, *(const bf16x8*)(vr + 32), acc[db], 0, 0, 0);
    }
  }

  float inv[4];
#pragma unroll
  for (int jj = 0; jj < 4; ++jj) inv[jj] = 1.0f / lrow[jj];
#pragma unroll
  for (int jj = 0; jj < 4; ++jj)
#pragma unroll
    for (int db = 0; db < 4; ++db)
      X[((size_t)b*T_ + q0 + kg*4 + jj)*D_ + h*DK_ + db*16 + r16] =
          f2bf(acc[db][jj] * inv[jj]);
}

extern "C" void kernel_launch(void* const* d_in, const int* in_sizes, int n_in,
                              void* d_out, int out_size, void* d_ws, size_t ws_size,
                              hipStream_t stream) {
  const float* qa    = (const float*)d_in[0];
  const float* query = (const float*)d_in[1];
  const float* key   = (const float*)d_in[2];
  const float* value = (const float*)d_in[3];
  const float* Wq = (const float*)d_in[4];
  const float* bq = (const float*)d_in[5];
  const float* Wk = (const float*)d_in[6];
  const float* bk = (const float*)d_in[7];
  const float* Wv = (const float*)d_in[8];
  const float* bv = (const float*)d_in[9];
  const float* Wo = (const float*)d_in[10];
  const float* bo = (const float*)d_in[11];
  const int* mask = (const int*)d_in[12];

  const size_t ND = (size_t)N_ * D_;
  const size_t DD = (size_t)D_ * D_;
  const size_t QAT = (size_t)B_ * C_ * T_ * T_;
  unsigned short* Qws = (unsigned short*)d_ws;
  unsigned short* Kws = Qws + ND;
  unsigned short* Vws = Kws + ND;
  unsigned short* Xws = Vws + ND;
  unsigned short* qbf = Xws + ND;     // doubles as Vt after the Q GEMM
  unsigned short* kbf = qbf + ND;
  unsigned short* vbf = kbf + ND;
  unsigned short* wqbf = vbf + ND;
  unsigned short* wkbf = wqbf + DD;
  unsigned short* wvbf = wkbf + DD;
  unsigned short* wobf = wvbf + DD;
  unsigned short* qatws = wobf + DD;  // fp16 qa_t [B][C][T][T]
  unsigned short* Vtws = qbf;

  bool fast = ws_size >= (7*ND + 4*DD + QAT) * sizeof(unsigned short);

  dim3 blk(256);
  cvt_qkv<<<3072, blk, 0, stream>>>(query, key, value, qbf, kbf, vbf, (int)(ND/4));
  cvt_w<<<1024, blk, 0, stream>>>(Wq, Wk, Wv, Wo, wqbf, wkbf, wvbf, wobf, (int)(DD/4));

  gemm_qkv<<<3*512, blk, 0, stream>>>(qbf, kbf, vbf, wqbf, wkbf, wvbf,
                                      bq, bk, bv, Qws, Kws, Vws);

  if (fast) {
    tv_tqa<<<2048 + 8192, blk, 0, stream>>>(Vws, Vtws, qa, qatws);
    attn4b<<<B_*H_*(T_/128), blk, 0, stream>>>(Qws, Kws, Vtws, qatws, mask, Xws);
  } else {
    transposeV<<<B_*H_*(T_/64), blk, 0, stream>>>(Vws, Vtws);
    attn_fused<<<B_*H_*(T_/64), blk, 0, stream>>>(Qws, Kws, Vtws, qa, mask, Xws);
  }

  gemm_lds<true><<<512, blk, 0, stream>>>(Xws, wobf, bo, (float*)d_out);
}

// Round 20
// 318.591 us; speedup vs baseline: 1.4634x; 1.0094x over previous
//
#include <hip/hip_runtime.h>

#define B_  8
#define T_  1024
#define D_  1024
#define H_  16
#define DK_ 64
#define C_  8
#define N_  (B_*T_)   // 8192 rows

typedef __attribute__((ext_vector_type(8))) short bf16x8;
typedef __attribute__((ext_vector_type(4))) float f32x4;
typedef __attribute__((ext_vector_type(8))) unsigned short u16x8;
typedef __attribute__((ext_vector_type(4))) unsigned short u16x4;

__device__ __forceinline__ float bf2f(unsigned short u) {
  union { unsigned int i; float f; } x; x.i = ((unsigned int)u) << 16; return x.f;
}
__device__ __forceinline__ unsigned short f2bf(float f) {
  union { float f; unsigned int i; } x; x.f = f;
  unsigned int r = (x.i + 0x7fffu + ((x.i >> 16) & 1u)) >> 16;
  return (unsigned short)r;
}
__device__ __forceinline__ unsigned short f2h(float f) {
  union { _Float16 h; unsigned short u; } x; x.h = (_Float16)f; return x.u;
}
__device__ __forceinline__ float h2f(unsigned short u) {
  union { _Float16 h; unsigned short u; } x; x.u = u; return (float)x.h;
}

// async global->LDS, 16B per lane. LDS dest is wave-uniform base + lane*16.
__device__ __forceinline__ void gl_lds16(const unsigned short* g, unsigned short* l) {
  __builtin_amdgcn_global_load_lds(
      (const __attribute__((address_space(1))) unsigned int*)g,
      (__attribute__((address_space(3))) unsigned int*)l,
      16, 0, 0);
}

// ---- ALL fp32->bf16 conversions in ONE launch (validated R12/R13) ---------
// grid 4096: seg 0..2 = q/k/v (1024 blocks each), seg 3 = 4 weights (256 each)
__global__ __launch_bounds__(256) void cvt_all(
    const float* __restrict__ q, const float* __restrict__ k,
    const float* __restrict__ v,
    const float* __restrict__ w0, const float* __restrict__ w1,
    const float* __restrict__ w2, const float* __restrict__ w3,
    unsigned short* __restrict__ qo, unsigned short* __restrict__ ko,
    unsigned short* __restrict__ vo,
    unsigned short* __restrict__ o0, unsigned short* __restrict__ o1,
    unsigned short* __restrict__ o2, unsigned short* __restrict__ o3,
    int n4q, int n4w) {
  int seg = blockIdx.x >> 10;
  const float* in;
  unsigned short* out;
  int tid, stride, n4;
  if (seg < 3) {
    in  = (seg == 0) ? q : (seg == 1) ? k : v;
    out = (seg == 0) ? qo : (seg == 1) ? ko : vo;
    tid = (blockIdx.x & 1023) * 256 + threadIdx.x;
    stride = 1024 * 256;
    n4 = n4q;
  } else {
    int sub = (blockIdx.x & 1023) >> 8;
    in  = (sub == 0) ? w0 : (sub == 1) ? w1 : (sub == 2) ? w2 : w3;
    out = (sub == 0) ? o0 : (sub == 1) ? o1 : (sub == 2) ? o2 : o3;
    tid = (blockIdx.x & 255) * 256 + threadIdx.x;
    stride = 256 * 256;
    n4 = n4w;
  }
  const float4* in4 = (const float4*)in;
  u16x4* out4 = (u16x4*)out;
  for (int i = tid; i < n4; i += stride) {
    float4 vv = in4[i];
    u16x4 o = { f2bf(vv.x), f2bf(vv.y), f2bf(vv.z), f2bf(vv.w) };
    out4[i] = o;
  }
}

// ---- transposeQa body: qa [B][T][T][C] fp32 -> qat [B][C][T][T] fp16 ------
__device__ __forceinline__ void tqa_body(
    int bid, const float* __restrict__ qa, unsigned short* __restrict__ qat,
    float (*L)[132]) {
  int b = bid >> 10, q = bid & 1023;
  int t = threadIdx.x;
  const float* src = qa + ((size_t)(b*T_ + q))*T_*C_;
  for (int ch = 0; ch < 8; ++ch) {
    int k0 = ch*128;
    float4 v = *(const float4*)(src + (size_t)(k0 + (t>>1))*C_ + (t&1)*4);
    int c4 = (t&1)*4, kk = t>>1;
    L[c4+0][kk] = v.x; L[c4+1][kk] = v.y; L[c4+2][kk] = v.z; L[c4+3][kk] = v.w;
    __syncthreads();
    int c = t >> 5, kk2 = (t&31)*4;
    float4 p = *(const float4*)&L[c][kk2];
    u16x4 o = { f2h(p.x), f2h(p.y), f2h(p.z), f2h(p.w) };
    *(u16x4*)(qat + ((size_t)(b*C_ + c)*T_ + q)*T_ + k0 + kk2) = o;
    __syncthreads();
  }
}

// ---- transposeV body: V [b*T+t][h*64+d] -> Vt [(b*H+h)*64+d][T] -----------
__device__ __forceinline__ void tv_body(
    int bid, const unsigned short* __restrict__ V, unsigned short* __restrict__ Vt,
    unsigned short (*L)[72]) {
  int tt = bid & 15;
  int bh = bid >> 4;               // 0..127
  int b = bh >> 4, h = bh & 15;
  int r  = threadIdx.x >> 3;       // 0..31
  int c8 = (threadIdx.x & 7) * 8;
  const unsigned short* src = V + ((size_t)(b*T_ + tt*64))*D_ + h*64;
#pragma unroll
  for (int p = 0; p < 2; ++p) {
    int rr = r + p*32;
    u16x8 v = *(const u16x8*)(src + (size_t)rr*D_ + c8);
    *(u16x8*)&L[rr][c8] = v;
  }
  __syncthreads();
  unsigned short* dst = Vt + ((size_t)bh*64)*T_ + tt*64;
#pragma unroll
  for (int p = 0; p < 2; ++p) {
    int d = r + p*32;
    u16x8 o;
#pragma unroll
    for (int i = 0; i < 8; ++i) o[i] = L[c8 + i][d];
    *(u16x8*)(dst + (size_t)d*T_ + c8) = o;
  }
}

// ---- fused transposeV + transposeQa (both pure-BW streamers, same regime) -
__global__ __launch_bounds__(256) void tv_tqa(
    const unsigned short* __restrict__ V, unsigned short* __restrict__ Vt,
    const float* __restrict__ qa, unsigned short* __restrict__ qat) {
  __shared__ __align__(16) unsigned char smem[9216];  // union of both bodies
  if (blockIdx.x < 2048) {
    tv_body(blockIdx.x, V, Vt, (unsigned short(*)[72])smem);
  } else {
    tqa_body(blockIdx.x - 2048, qa, qat, (float(*)[132])smem);
  }
}

// standalone versions (fallback path)
__global__ __launch_bounds__(256) void transposeQa(
    const float* __restrict__ qa, unsigned short* __restrict__ qat) {
  __shared__ float L[8][132];
  tqa_body(blockIdx.x, qa, qat, L);
}
__global__ __launch_bounds__(256) void transposeV(
    const unsigned short* __restrict__ V, unsigned short* __restrict__ Vt) {
  __shared__ unsigned short L[64][72];
  tv_body(blockIdx.x, V, Vt, L);
}

// ---------------- m97-structure GEMM body: 128x128 tile, BK=32, 4 waves ----
template <bool OUT_F32>
__device__ __forceinline__ void gemm_body(
    int blockid, const unsigned short* __restrict__ X,
    const unsigned short* __restrict__ W, const float* __restrict__ bias,
    void* __restrict__ Yv, unsigned short* As, unsigned short* Bs) {
  int orig = (blockid & 7) * 64 + (blockid >> 3);   // bijective (512%8==0)
  int bm = orig >> 3, bn = orig & 7;
  int t = threadIdx.x, lane = t & 63, w = t >> 6;
  int wr = w >> 1, wc = w & 1;
  int r16 = lane & 15, kg = lane >> 4;

  int srow0 = lane >> 2;
  int scol  = (lane & 3) * 8;
  const unsigned short* Ab = X + (size_t)(bm*128)*D_ + scol;
  const unsigned short* Bb = W + (size_t)(bn*128)*D_ + scol;

  f32x4 acc[4][4];
#pragma unroll
  for (int m = 0; m < 4; ++m)
#pragma unroll
    for (int n = 0; n < 4; ++n) acc[m][n] = (f32x4){0.f,0.f,0.f,0.f};

  for (int k0 = 0; k0 < D_; k0 += 32) {
    __syncthreads();
#pragma unroll
    for (int c = 0; c < 2; ++c) {
      int cidx = w*2 + c;
      int row = cidx*16 + srow0;
      gl_lds16(Ab + (size_t)row*D_ + k0, As + cidx*512);
      gl_lds16(Bb + (size_t)row*D_ + k0, Bs + cidx*512);
    }
    __syncthreads();

    bf16x8 a[4], bb[4];
#pragma unroll
    for (int m = 0; m < 4; ++m)
      a[m] = *(const bf16x8*)(As + (wr*64 + m*16 + r16)*32 + kg*8);
#pragma unroll
    for (int n = 0; n < 4; ++n)
      bb[n] = *(const bf16x8*)(Bs + (wc*64 + n*16 + r16)*32 + kg*8);
#pragma unroll
    for (int m = 0; m < 4; ++m)
#pragma unroll
      for (int n = 0; n < 4; ++n)
        acc[m][n] = __builtin_amdgcn_mfma_f32_16x16x32_bf16(a[m], bb[n], acc[m][n], 0, 0, 0);
  }

#pragma unroll
  for (int n = 0; n < 4; ++n) {
    int col = bn*128 + wc*64 + n*16 + r16;
    float bv = bias[col];
#pragma unroll
    for (int m = 0; m < 4; ++m) {
      int row0 = bm*128 + wr*64 + m*16 + kg*4;
#pragma unroll
      for (int jj = 0; jj < 4; ++jj) {
        float rv = acc[m][n][jj] + bv;
        if constexpr (OUT_F32)
          ((float*)Yv)[(size_t)(row0 + jj)*D_ + col] = rv;
        else
          ((unsigned short*)Yv)[(size_t)(row0 + jj)*D_ + col] = f2bf(rv);
      }
    }
  }
}

// single GEMM (used for the output projection)
template <bool OUT_F32>
__global__ __launch_bounds__(256) void gemm_lds(
    const unsigned short* __restrict__ X, const unsigned short* __restrict__ W,
    const float* __restrict__ bias, void* __restrict__ Yv) {
  __shared__ __align__(16) unsigned short As[128*32];
  __shared__ __align__(16) unsigned short Bs[128*32];
  gemm_body<OUT_F32>(blockIdx.x, X, W, bias, Yv, As, Bs);
}

// fused Q/K/V projections: grid = 3*512, segment-decoded
__global__ __launch_bounds__(256) void gemm_qkv(
    const unsigned short* __restrict__ Xq, const unsigned short* __restrict__ Xk,
    const unsigned short* __restrict__ Xv,
    const unsigned short* __restrict__ Wq2, const unsigned short* __restrict__ Wk2,
    const unsigned short* __restrict__ Wv2,
    const float* __restrict__ bq2, const float* __restrict__ bk2,
    const float* __restrict__ bv2,
    unsigned short* __restrict__ Yq, unsigned short* __restrict__ Yk,
    unsigned short* __restrict__ Yv2) {
  __shared__ __align__(16) unsigned short As[128*32];
  __shared__ __align__(16) unsigned short Bs[128*32];
  int seg = blockIdx.x >> 9, inner = blockIdx.x & 511;
  const unsigned short* X = (seg == 0) ? Xq : (seg == 1) ? Xk : Xv;
  const unsigned short* W = (seg == 0) ? Wq2 : (seg == 1) ? Wk2 : Wv2;
  const float* bias = (seg == 0) ? bq2 : (seg == 1) ? bk2 : bv2;
  unsigned short* Y = (seg == 0) ? Yq : (seg == 1) ? Yk : Yv2;
  gemm_body<false>(inner, X, W, bias, Y, As, Bs);
}

// ---------------- attn4b (proven ~128us): single-fence + deferred lsum -----
// block = (b,h,128 q-rows); wave w owns q = q0w..q0w+31 (2 q-frags of 16).
// K/V tiles double-buffered LDS (both-sides swizzle); swapped QK^T; per-qf
// P buffers so ONE lgkm fence serves both PV blocks; lsum kept per-lane
// partial (reduced in epilogue); rescale skipped unless row-max grew > 8.
// FINAL: occ-3 / ~84 VGPR is this kernel's structural optimum. All register-
// widening edits spill (R10 qa-prefetch, R12 vf-hoist, R16 occ-4, R18
// shuffle-P); scheduling edits neutral (R15). Do not modify.
__global__ __launch_bounds__(256, 3) void attn4b(
    const unsigned short* __restrict__ Q, const unsigned short* __restrict__ K,
    const unsigned short* __restrict__ Vt, const unsigned short* __restrict__ qat,
    const int* __restrict__ mask, unsigned short* __restrict__ X) {
  int swzid = ((blockIdx.x & 7) << 7) | (blockIdx.x >> 3);  // XCD-chunked, 1024
  int qt = swzid & 7, h = (swzid >> 3) & 15, b = swzid >> 7;
  int w = threadIdx.x >> 6, lane = threadIdx.x & 63;
  int r16 = lane & 15, kg = lane >> 4;
  int q0w = qt*128 + w*32;
  int bh = b*H_ + h;

  __shared__ unsigned short Ks[2][64][64];    // 16 KB
  __shared__ unsigned short Vs[2][64][64];    // 16 KB
  __shared__ unsigned int  P32[4][2][16][32]; // 16 KB, per (wave, qf)

  int rl = lane >> 3;
  int eo = ((lane & 7) * 8) ^ (rl << 3);     // swizzled elem offset in row
  const unsigned short* Kb = K + ((size_t)b*T_)*D_ + h*DK_;
  const unsigned short* Vb = Vt + ((size_t)bh*DK_)*T_;

  int sw16 = (r16 & 7) << 4;
  int ko0 = ((kg*16 +  0) ^ sw16) >> 1;      // elem offset, half 0
  int ko1 = ((kg*16 + 64) ^ sw16) >> 1;      // elem offset, half 1
  int sw32 = (r16 & 7) << 2;                 // word swizzle for P

  bf16x8 qfr[2][2];
#pragma unroll
  for (int qf = 0; qf < 2; ++qf) {
    const unsigned short* qrow = Q + ((size_t)b*T_ + q0w + qf*16 + r16)*D_ + h*DK_ + kg*8;
    qfr[qf][0] = *(const bf16x8*)qrow;
    qfr[qf][1] = *(const bf16x8*)(qrow + 32);
  }

  f32x4 acc[2][4];
#pragma unroll
  for (int qf = 0; qf < 2; ++qf)
#pragma unroll
    for (int db = 0; db < 4; ++db) acc[qf][db] = (f32x4){0.f,0.f,0.f,0.f};
  float mold[2] = {-3e38f, -3e38f};
  float lpart[2] = {0.f, 0.f};    // per-lane partial denominator (16 k each)

  const int* mrow = mask + b*T_;
  const unsigned short* qab0 = qat + ((size_t)((b*C_ + h)*T_) + q0w + r16)*T_;

  // prologue: stage tile 0 into buffer 0
#pragma unroll
  for (int c = 0; c < 2; ++c) {
    int cc = w*2 + c;
    gl_lds16(Kb + (size_t)(cc*8 + rl)*D_ + eo, &Ks[0][cc*8][0]);
    gl_lds16(Vb + (size_t)(cc*8 + rl)*T_ + eo, &Vs[0][cc*8][0]);
  }
  __syncthreads();

  for (int t = 0; t < 16; ++t) {
    int k0 = t*64, bb = t & 1;
    // ---- stage next tile into other buffer ----
    if (t < 15) {
      int kn = k0 + 64, nb = bb ^ 1;
#pragma unroll
      for (int c = 0; c < 2; ++c) {
        int cc = w*2 + c;
        gl_lds16(Kb + (size_t)(kn + cc*8 + rl)*D_ + eo, &Ks[nb][cc*8][0]);
        gl_lds16(Vb + (size_t)(cc*8 + rl)*T_ + kn + eo, &Vs[nb][cc*8][0]);
      }
    }
    // ---- qa + mask loads ----
    u16x4 qv[2][4];
    if (h < C_) {
#pragma unroll
      for (int qf = 0; qf < 2; ++qf)
#pragma unroll
        for (int kt = 0; kt < 4; ++kt)
          qv[qf][kt] = *(const u16x4*)(qab0 + (size_t)qf*16*T_ + k0 + kt*16 + kg*4);
    }
    int mk = mrow[k0 + lane];
    unsigned long long bits = __ballot(mk != 0);

    // ---- QK^T from LDS: s[qf][kt], rows=k cols=q ----
    f32x4 s[2][4];
#pragma unroll
    for (int kt = 0; kt < 4; ++kt) {
      bf16x8 kf0 = *(const bf16x8*)&Ks[bb][kt*16 + r16][ko0];
      bf16x8 kf1 = *(const bf16x8*)&Ks[bb][kt*16 + r16][ko1];
#pragma unroll
      for (int qf = 0; qf < 2; ++qf) {
        f32x4 z = (f32x4){0.f,0.f,0.f,0.f};
        z = __builtin_amdgcn_mfma_f32_16x16x32_bf16(kf0, qfr[qf][0], z, 0, 0, 0);
        z = __builtin_amdgcn_mfma_f32_16x16x32_bf16(kf1, qfr[qf][1], z, 0, 0, 0);
        s[qf][kt] = z;
      }
    }

    // ---- scale + bias + mask; row-max per q-frag (2 shfl each) ----
    float pmaxq[2];
#pragma unroll
    for (int qf = 0; qf < 2; ++qf) {
      float pmax = -3e38f;
#pragma unroll
      for (int kt = 0; kt < 4; ++kt)
#pragma unroll
        for (int jj = 0; jj < 4; ++jj) {
          float v = s[qf][kt][jj] * 0.125f;
          if (h < C_) v += 5.0f * h2f(qv[qf][kt][jj]);
          int idx = kt*16 + kg*4 + jj;
          v = ((bits >> idx) & 1ULL) ? v : -1e9f;
          s[qf][kt][jj] = v;
          pmax = fmaxf(pmax, v);
        }
      pmax = fmaxf(pmax, __shfl_xor(pmax, 16, 64));
      pmax = fmaxf(pmax, __shfl_xor(pmax, 32, 64));
      pmaxq[qf] = pmax;
    }
    // ---- defer-max: rescale only when a row's max grew by > 8 ----
    if (!__all(pmaxq[0] - mold[0] <= 8.0f && pmaxq[1] - mold[1] <= 8.0f)) {
#pragma unroll
      for (int qf = 0; qf < 2; ++qf) {
        float mnew = fmaxf(mold[qf], pmaxq[qf]);
        float sc = __expf(mold[qf] - mnew);
        mold[qf] = mnew;
        lpart[qf] *= sc;
        float scq[4];
#pragma unroll
        for (int jj = 0; jj < 4; ++jj) scq[jj] = __shfl(sc, kg*4 + jj, 64);
#pragma unroll
        for (int db = 0; db < 4; ++db)
#pragma unroll
          for (int jj = 0; jj < 4; ++jj) acc[qf][db][jj] *= scq[jj];
      }
    }
    // ---- exp + pack + P write, both q-frags; ONE fence ----
#pragma unroll
    for (int qf = 0; qf < 2; ++qf) {
      unsigned int pk[8];
#pragma unroll
      for (int kt = 0; kt < 4; ++kt) {
        float p0 = __expf(s[qf][kt][0] - mold[qf]), p1 = __expf(s[qf][kt][1] - mold[qf]);
        float p2 = __expf(s[qf][kt][2] - mold[qf]), p3 = __expf(s[qf][kt][3] - mold[qf]);
        lpart[qf] += (p0 + p1) + (p2 + p3);
        pk[kt*2+0] = (unsigned)f2bf(p0) | ((unsigned)f2bf(p1) << 16);
        pk[kt*2+1] = (unsigned)f2bf(p2) | ((unsigned)f2bf(p3) << 16);
      }
#pragma unroll
      for (int kt = 0; kt < 4; ++kt)
        *(uint2*)&P32[w][qf][r16][(kt*8 + kg*2) ^ sw32] =
            make_uint2(pk[kt*2], pk[kt*2+1]);
    }
    asm volatile("s_waitcnt lgkmcnt(0)" ::: "memory");
    __builtin_amdgcn_sched_barrier(0);
    // ---- PV for both q-frags (16 contiguous MFMAs) ----
#pragma unroll
    for (int qf = 0; qf < 2; ++qf) {
      bf16x8 pa0 = *(const bf16x8*)&P32[w][qf][r16][(kg*4) ^ sw32];
      bf16x8 pa1 = *(const bf16x8*)&P32[w][qf][r16][(16 + kg*4) ^ sw32];
#pragma unroll
      for (int db = 0; db < 4; ++db) {
        bf16x8 vf0 = *(const bf16x8*)&Vs[bb][db*16 + r16][ko0];
        bf16x8 vf1 = *(const bf16x8*)&Vs[bb][db*16 + r16][ko1];
        acc[qf][db] = __builtin_amdgcn_mfma_f32_16x16x32_bf16(pa0, vf0, acc[qf][db], 0, 0, 0);
        acc[qf][db] = __builtin_amdgcn_mfma_f32_16x16x32_bf16(pa1, vf1, acc[qf][db], 0, 0, 0);
      }
    }
    __syncthreads();   // drains vmcnt (stage) + lgkm; next tile ready
  }

  // epilogue: reduce partial denominators across the 4 kg-lanes, normalize
#pragma unroll
  for (int qf = 0; qf < 2; ++qf) {
    float lp = lpart[qf];
    lp += __shfl_xor(lp, 16, 64);
    lp += __shfl_xor(lp, 32, 64);
    float linv = 1.0f / lp;
    float invq[4];
#pragma unroll
    for (int jj = 0; jj < 4; ++jj) invq[jj] = __shfl(linv, kg*4 + jj, 64);
#pragma unroll
    for (int jj = 0; jj < 4; ++jj)
#pragma unroll
      for (int db = 0; db < 4; ++db)
        X[((size_t)b*T_ + q0w + qf*16 + kg*4 + jj)*D_ + h*DK_ + db*16 + r16] =
            f2bf(acc[qf][db][jj] * invq[jj]);
  }
}

// ---------------- fallback attention (fp32 qa direct, block barriers) ------
__global__ __launch_bounds__(256) void attn_fused(
    const unsigned short* __restrict__ Q, const unsigned short* __restrict__ K,
    const unsigned short* __restrict__ Vt, const float* __restrict__ qa,
    const int* __restrict__ mask, unsigned short* __restrict__ X) {
  int bid = blockIdx.x;
  int qt = bid & 15, h = (bid >> 4) & 15, b = bid >> 8;
  int w = threadIdx.x >> 6, lane = threadIdx.x & 63;
  int r16 = lane & 15, kg = lane >> 4;
  int q0 = qt*64 + w*16;
  int bh = b*H_ + h;

  __shared__ unsigned short P[4][16][72];

  const unsigned short* qrow = Q + ((size_t)b*T_ + q0 + r16)*D_ + h*DK_ + kg*8;
  bf16x8 qf0 = *(const bf16x8*)qrow;
  bf16x8 qf1 = *(const bf16x8*)(qrow + 32);

  f32x4 acc[4];
#pragma unroll
  for (int db = 0; db < 4; ++db) acc[db] = (f32x4){0.f,0.f,0.f,0.f};
  float mrow[4], lrow[4];
#pragma unroll
  for (int jj = 0; jj < 4; ++jj) { mrow[jj] = -3e38f; lrow[jj] = 0.f; }

  const int* mptr = mask + b*T_;
  const unsigned short* Kbase = K + ((size_t)b*T_)*D_ + h*DK_;
  const unsigned short* Vbase = Vt + ((size_t)bh*DK_)*T_;
  const float* qabase = qa + ((size_t)(b*T_ + q0 + kg*4))*T_*C_ + h;

  for (int k0 = 0; k0 < T_; k0 += 64) {
    f32x4 s[4];
#pragma unroll
    for (int kt = 0; kt < 4; ++kt) {
      const unsigned short* krow = Kbase + (size_t)(k0 + kt*16 + r16)*D_ + kg*8;
      f32x4 z = (f32x4){0.f,0.f,0.f,0.f};
      z = __builtin_amdgcn_mfma_f32_16x16x32_bf16(qf0, *(const bf16x8*)krow,        z, 0, 0, 0);
      z = __builtin_amdgcn_mfma_f32_16x16x32_bf16(qf1, *(const bf16x8*)(krow + 32), z, 0, 0, 0);
      s[kt] = z;
    }
    int mk[4];
#pragma unroll
    for (int kt = 0; kt < 4; ++kt) mk[kt] = mptr[k0 + kt*16 + r16];
    if (h < C_) {
#pragma unroll
      for (int kt = 0; kt < 4; ++kt)
#pragma unroll
        for (int jj = 0; jj < 4; ++jj) {
          float bb = qabase[(size_t)jj*T_*C_ + (size_t)(k0 + kt*16 + r16)*C_];
          s[kt][jj] = s[kt][jj]*0.125f + 5.0f*bb;
        }
    } else {
#pragma unroll
      for (int kt = 0; kt < 4; ++kt)
#pragma unroll
        for (int jj = 0; jj < 4; ++jj) s[kt][jj] *= 0.125f;
    }
#pragma unroll
    for (int kt = 0; kt < 4; ++kt)
#pragma unroll
      for (int jj = 0; jj < 4; ++jj)
        if (mk[kt] == 0) s[kt][jj] = -1e9f;

#pragma unroll
    for (int jj = 0; jj < 4; ++jj) {
      float v = fmaxf(fmaxf(s[0][jj], s[1][jj]), fmaxf(s[2][jj], s[3][jj]));
#pragma unroll
      for (int d = 1; d < 16; d <<= 1) v = fmaxf(v, __shfl_xor(v, d, 64));
      float mnew = fmaxf(mrow[jj], v);
      float sc = __expf(mrow[jj] - mnew);
      mrow[jj] = mnew;
      lrow[jj] *= sc;
#pragma unroll
      for (int db = 0; db < 4; ++db) acc[db][jj] *= sc;
      float rs = 0.f;
#pragma unroll
      for (int kt = 0; kt < 4; ++kt) {
        float p = __expf(s[kt][jj] - mnew);
        rs += p;
        P[w][kg*4 + jj][kt*16 + r16] = f2bf(p);
      }
#pragma unroll
      for (int d = 1; d < 16; d <<= 1) rs += __shfl_xor(rs, d, 64);
      lrow[jj] += rs;
    }
    __syncthreads();

    bf16x8 pa0 = *(const bf16x8*)&P[w][r16][kg*8];
    bf16x8 pa1 = *(const bf16x8*)&P[w][r16][32 + kg*8];
#pragma unroll
    for (int db = 0; db < 4; ++db) {
      const unsigned short* vr = Vbase + (size_t)(db*16 + r16)*T_ + k0 + kg*8;
      acc[db] = __builtin_amdgcn_mfma_f32_16x16x32_bf16(pa0, *(const bf16x8*)vr,        acc[db], 0, 0, 0);
      acc[db] = __builtin_amdgcn_mfma_f32_16x16x32_bf16(pa1, *(const bf16x8*)(vr + 32), acc[db], 0, 0, 0);
    }
  }

  float inv[4];
#pragma unroll
  for (int jj = 0; jj < 4; ++jj) inv[jj] = 1.0f / lrow[jj];
#pragma unroll
  for (int jj = 0; jj < 4; ++jj)
#pragma unroll
    for (int db = 0; db < 4; ++db)
      X[((size_t)b*T_ + q0 + kg*4 + jj)*D_ + h*DK_ + db*16 + r16] =
          f2bf(acc[db][jj] * inv[jj]);
}

extern "C" void kernel_launch(void* const* d_in, const int* in_sizes, int n_in,
                              void* d_out, int out_size, void* d_ws, size_t ws_size,
                              hipStream_t stream) {
  const float* qa    = (const float*)d_in[0];
  const float* query = (const float*)d_in[1];
  const float* key   = (const float*)d_in[2];
  const float* value = (const float*)d_in[3];
  const float* Wq = (const float*)d_in[4];
  const float* bq = (const float*)d_in[5];
  const float* Wk = (const float*)d_in[6];
  const float* bk = (const float*)d_in[7];
  const float* Wv = (const float*)d_in[8];
  const float* bv = (const float*)d_in[9];
  const float* Wo = (const float*)d_in[10];
  const float* bo = (const float*)d_in[11];
  const int* mask = (const int*)d_in[12];

  const size_t ND = (size_t)N_ * D_;
  const size_t DD = (size_t)D_ * D_;
  const size_t QAT = (size_t)B_ * C_ * T_ * T_;
  unsigned short* Qws = (unsigned short*)d_ws;
  unsigned short* Kws = Qws + ND;
  unsigned short* Vws = Kws + ND;
  unsigned short* Xws = Vws + ND;
  unsigned short* qbf = Xws + ND;     // doubles as Vt after the Q GEMM
  unsigned short* kbf = qbf + ND;
  unsigned short* vbf = kbf + ND;
  unsigned short* wqbf = vbf + ND;
  unsigned short* wkbf = wqbf + DD;
  unsigned short* wvbf = wkbf + DD;
  unsigned short* wobf = wvbf + DD;
  unsigned short* qatws = wobf + DD;  // fp16 qa_t [B][C][T][T]
  unsigned short* Vtws = qbf;

  bool fast = ws_size >= (7*ND + 4*DD + QAT) * sizeof(unsigned short);

  dim3 blk(256);
  cvt_all<<<4096, blk, 0, stream>>>(query, key, value, Wq, Wk, Wv, Wo,
                                    qbf, kbf, vbf, wqbf, wkbf, wvbf, wobf,
                                    (int)(ND/4), (int)(DD/4));

  gemm_qkv<<<3*512, blk, 0, stream>>>(qbf, kbf, vbf, wqbf, wkbf, wvbf,
                                      bq, bk, bv, Qws, Kws, Vws);

  if (fast) {
    tv_tqa<<<2048 + 8192, blk, 0, stream>>>(Vws, Vtws, qa, qatws);
    attn4b<<<B_*H_*(T_/128), blk, 0, stream>>>(Qws, Kws, Vtws, qatws, mask, Xws);
  } else {
    transposeV<<<B_*H_*(T_/64), blk, 0, stream>>>(Vws, Vtws);
    attn_fused<<<B_*H_*(T_/64), blk, 0, stream>>>(Qws, Kws, Vtws, qa, mask, Xws);
  }

  gemm_lds<true><<<512, blk, 0, stream>>>(Xws, wobf, bo, (float*)d_out);
}